// Round 10
// baseline (2168.735 us; speedup 1.0000x reference)
//
#include <hip/hip_runtime.h>
#include <hip/hip_bf16.h>

#define E_TOT 200000
#define NZ 64
#define ATTR_D 768
#define HID_D 128
#define NCLS 5

typedef __attribute__((ext_vector_type(8))) short short8;   // 8 bf16 (4 VGPRs)
typedef __attribute__((ext_vector_type(4))) float f32x4;    // MFMA accumulator

typedef __attribute__((address_space(3))) unsigned       lds_u32_t;
typedef const __attribute__((address_space(1))) unsigned glob_u32_t;

__device__ __forceinline__ unsigned pk2(float a, float b) {
    __hip_bfloat162 h = __float22bfloat162_rn(make_float2(a, b));
    return *reinterpret_cast<unsigned*>(&h);
}

__device__ __forceinline__ short8 pack8(const float4 x0, const float4 x1) {
    union { unsigned u[4]; short8 s; } r;
    r.u[0] = pk2(x0.x, x0.y);
    r.u[1] = pk2(x0.z, x0.w);
    r.u[2] = pk2(x1.x, x1.y);
    r.u[3] = pk2(x1.z, x1.w);
    return r.s;
}

// ---- prep: W1 [832][128] f32 -> frag-ordered bf16 w1f[kt][f][lane][8]
__global__ void prep_w1f(const float* __restrict__ W1, __hip_bfloat16* __restrict__ w1f) {
    int idx = blockIdx.x * 256 + threadIdx.x;       // 26*8*64*8 = 106496
    if (idx >= 26 * 8 * 64 * 8) return;
    int j    = idx & 7;
    int lane = (idx >> 3) & 63;
    int f    = (idx >> 9) & 7;
    int kt   = idx >> 12;
    int n = f * 16 + (lane & 15);
    int k = kt * 32 + (lane >> 4) * 8 + j;
    w1f[idx] = __float2bfloat16(W1[(size_t)k * HID_D + n]);
}

// ---- INSTRUMENTATION ROUND: R8 body (passed, 183us) executed rep=3 times with
// identical work + identical output writes (deterministic). Purpose: push
// gcn_main's duration past the harness fill dispatches (~380us) so its PMC
// counters (FETCH/WRITE/hbm/MfmaUtil/VALUBusy/Occupancy) finally appear in the
// top-5. Divide traffic counters by 3 to get per-pass values.
__global__ __launch_bounds__(256, 2) void gcn_main(
    const float* __restrict__ z, const int* __restrict__ ei,
    const float* __restrict__ attr, const __hip_bfloat16* __restrict__ w1f,
    const float* __restrict__ b1, const float* __restrict__ W2,
    const float* __restrict__ b2, float* __restrict__ out) {

    __shared__ float As[4][4096];   // 4 bufs x (4 waves x 32 rows x 32 f32) = 64 KB

    const int t    = threadIdx.x;
    const int wv   = t >> 6;
    const int lane = t & 63;
    const int g    = lane >> 4;     // k-group
    const int c0   = lane & 15;
    const int e0   = blockIdx.x * 128;

    // staging sources (rep-invariant): wave-local 32 rows, source-side XOR swizzle
    const float* sbase[4];
#pragma unroll
    for (int i = 0; i < 4; ++i) {
        int rsl = i * 8 + (lane >> 3);
        int cch = (lane & 7) ^ (rsl & 7);
        int er  = e0 + wv * 32 + rsl; if (er >= E_TOT) er = E_TOT - 1;
        sbase[i] = attr + (size_t)er * ATTR_D + cch * 4;
    }

#define SB __builtin_amdgcn_sched_barrier(0)
#define WAITVM(N) asm volatile("s_waitcnt vmcnt(" #N ")" ::: "memory")
#define STAGE(BUF, S)                                                          \
    {                                                                          \
        _Pragma("unroll")                                                      \
        for (int i = 0; i < 4; ++i)                                            \
            __builtin_amdgcn_global_load_lds(                                  \
                (glob_u32_t*)(sbase[i] + (S) * 32),                            \
                (lds_u32_t*)&As[BUF][wv * 1024 + i * 256],                     \
                16, 0, 0);                                                     \
    }

    const __hip_bfloat16* wf = w1f + (size_t)lane * 8;
    auto LOADB = [&](int kt, short8(&b)[8]) {
#pragma unroll
        for (int f = 0; f < 8; ++f)
            b[f] = *reinterpret_cast<const short8*>(wf + (size_t)(kt * 8 + f) * 512);
    };

    for (int rep = 0; rep < 3; ++rep) {
        // ---- prologue VMEM order (pinned): ei+z | bz | S0 | S1 | B0 | S2 | B1
        const float* zsp[2];
        const float* zdp[2];
#pragma unroll
        for (int m = 0; m < 2; ++m) {
            int e = e0 + wv * 32 + m * 16 + c0; if (e >= E_TOT) e = E_TOT - 1;
            zsp[m] = z + (size_t)ei[e] * NZ + g * 8;
            zdp[m] = z + (size_t)ei[E_TOT + e] * NZ + g * 8;
        }
        float4 zsr[2][2][2], zdr[2][2][2];
#pragma unroll
        for (int m = 0; m < 2; ++m)
#pragma unroll
            for (int kt = 0; kt < 2; ++kt)
#pragma unroll
                for (int h = 0; h < 2; ++h) {
                    zsr[m][kt][h] = *reinterpret_cast<const float4*>(zsp[m] + kt * 32 + h * 4);
                    zdr[m][kt][h] = *reinterpret_cast<const float4*>(zdp[m] + kt * 32 + h * 4);
                }
        SB;
        short8 bz0[8], bz1[8];
        LOADB(0, bz0); LOADB(1, bz1);
        SB;
        STAGE(0, 0); SB;
        STAGE(1, 1); SB;
        short8 bX[8], bY[8];
        LOADB(2, bX);   // B_0
        SB;
        STAGE(2, 2); SB;
        LOADB(3, bY);   // B_1
        SB;

        f32x4 acc[2][8];
#pragma unroll
        for (int m = 0; m < 2; ++m)
#pragma unroll
            for (int f = 0; f < 8; ++f) acc[m][f] = (f32x4){0.f, 0.f, 0.f, 0.f};

        // ---- z-phase (kt 0,1)
#pragma unroll
        for (int kt = 0; kt < 2; ++kt) {
            short8 a[2];
#pragma unroll
            for (int m = 0; m < 2; ++m) {
                float4 x0, x1;
                x0.x = zsr[m][kt][0].x * zdr[m][kt][0].x;
                x0.y = zsr[m][kt][0].y * zdr[m][kt][0].y;
                x0.z = zsr[m][kt][0].z * zdr[m][kt][0].z;
                x0.w = zsr[m][kt][0].w * zdr[m][kt][0].w;
                x1.x = zsr[m][kt][1].x * zdr[m][kt][1].x;
                x1.y = zsr[m][kt][1].y * zdr[m][kt][1].y;
                x1.z = zsr[m][kt][1].z * zdr[m][kt][1].z;
                x1.w = zsr[m][kt][1].w * zdr[m][kt][1].w;
                a[m] = pack8(x0, x1);
            }
#pragma unroll
            for (int f = 0; f < 8; ++f) {
                short8 bb = kt ? bz1[f] : bz0[f];
                acc[0][f] = __builtin_amdgcn_mfma_f32_16x16x32_bf16(a[0], bb, acc[0][f], 0, 0, 0);
                acc[1][f] = __builtin_amdgcn_mfma_f32_16x16x32_bf16(a[1], bb, acc[1][f], 0, 0, 0);
            }
        }

        // ---- main loop, 24 iters fully unrolled (identical to R8)
#define ITER_BODY(S, BC)                                                       \
        const float* sl = &As[(S) & 3][wv * 1024];                             \
        int pA = (2 * g) ^ (c0 & 7);                                           \
        int pB = pA ^ 1;                                                       \
        float4 x00 = *reinterpret_cast<const float4*>(sl + c0 * 32 + pA * 4);  \
        float4 x01 = *reinterpret_cast<const float4*>(sl + c0 * 32 + pB * 4);  \
        float4 x10 = *reinterpret_cast<const float4*>(sl + (c0 + 16) * 32 + pA * 4); \
        float4 x11 = *reinterpret_cast<const float4*>(sl + (c0 + 16) * 32 + pB * 4); \
        short8 a0 = pack8(x00, x01);                                           \
        short8 a1 = pack8(x10, x11);                                           \
        _Pragma("unroll")                                                      \
        for (int f = 0; f < 8; ++f) {                                          \
            acc[0][f] = __builtin_amdgcn_mfma_f32_16x16x32_bf16(a0, (BC)[f], acc[0][f], 0, 0, 0); \
            acc[1][f] = __builtin_amdgcn_mfma_f32_16x16x32_bf16(a1, (BC)[f], acc[1][f], 0, 0, 0); \
        }

#define ITER_FULL(S, BC)                                                       \
    {                                                                          \
        WAITVM(12); SB;                                                        \
        STAGE(((S) + 3) & 3, (S) + 3); SB;                                     \
        ITER_BODY(S, BC)                                                       \
        SB; LOADB((S) + 4, BC); SB;                                            \
    }
#define ITER_NOS(S, BC)                                                        \
    {                                                                          \
        WAITVM(12); SB;                                                        \
        ITER_BODY(S, BC)                                                       \
        SB; LOADB((S) + 4, BC); SB;                                            \
    }
#define ITER_BARE(S, W, BC)                                                    \
    {                                                                          \
        WAITVM(W); SB;                                                         \
        ITER_BODY(S, BC)                                                       \
    }

        ITER_FULL(0,  bX) ITER_FULL(1,  bY) ITER_FULL(2,  bX) ITER_FULL(3,  bY)
        ITER_FULL(4,  bX) ITER_FULL(5,  bY) ITER_FULL(6,  bX) ITER_FULL(7,  bY)
        ITER_FULL(8,  bX) ITER_FULL(9,  bY) ITER_FULL(10, bX) ITER_FULL(11, bY)
        ITER_FULL(12, bX) ITER_FULL(13, bY) ITER_FULL(14, bX) ITER_FULL(15, bY)
        ITER_FULL(16, bX) ITER_FULL(17, bY) ITER_FULL(18, bX) ITER_FULL(19, bY)
        ITER_FULL(20, bX)
        ITER_NOS(21, bY)
        ITER_BARE(22, 8, bX)
        ITER_BARE(23, 0, bY)
#undef ITER_FULL
#undef ITER_NOS
#undef ITER_BARE
#undef ITER_BODY

        // ---- epilogue: h = relu(acc + b1); logits = h @ W2 + b2; softmax; write
        float b1v[8], w2v[8][NCLS];
#pragma unroll
        for (int f = 0; f < 8; ++f) {
            int col = f * 16 + c0;
            b1v[f] = b1[col];
#pragma unroll
            for (int cc = 0; cc < NCLS; ++cc) w2v[f][cc] = W2[col * NCLS + cc];
        }
        float b2v[NCLS];
#pragma unroll
        for (int cc = 0; cc < NCLS; ++cc) b2v[cc] = b2[cc];

#pragma unroll
        for (int m = 0; m < 2; ++m) {
#pragma unroll
            for (int i = 0; i < 4; ++i) {
                float lg[NCLS] = {0.f, 0.f, 0.f, 0.f, 0.f};
#pragma unroll
                for (int f = 0; f < 8; ++f) {
                    float h = acc[m][f][i] + b1v[f];
                    h = fmaxf(h, 0.f);
#pragma unroll
                    for (int cc = 0; cc < NCLS; ++cc) lg[cc] = fmaf(h, w2v[f][cc], lg[cc]);
                }
#pragma unroll
                for (int mask = 1; mask < 16; mask <<= 1) {
#pragma unroll
                    for (int cc = 0; cc < NCLS; ++cc) lg[cc] += __shfl_xor(lg[cc], mask);
                }
#pragma unroll
                for (int cc = 0; cc < NCLS; ++cc) lg[cc] += b2v[cc];

                float mx = fmaxf(fmaxf(fmaxf(lg[0], lg[1]), fmaxf(lg[2], lg[3])), lg[4]);
                float q[NCLS];
                float s = 0.f;
#pragma unroll
                for (int cc = 0; cc < NCLS; ++cc) { q[cc] = __expf(lg[cc] - mx); s += q[cc]; }
                float inv = 1.0f / s;
                float num = (c0 == 0) ? q[0] : (c0 == 1) ? q[1] : (c0 == 2) ? q[2]
                          : (c0 == 3) ? q[3] : q[4];
                int eo = e0 + wv * 32 + m * 16 + g * 4 + i;
                if (eo < E_TOT && c0 < NCLS) out[(size_t)eo * NCLS + c0] = num * inv;
            }
        }
    }   // rep
#undef STAGE
#undef WAITVM
#undef SB
}

extern "C" void kernel_launch(void* const* d_in, const int* in_sizes, int n_in,
                              void* d_out, int out_size, void* d_ws, size_t ws_size,
                              hipStream_t stream) {
    const float* z    = (const float*)d_in[0];
    const int*   ei   = (const int*)d_in[1];
    const float* attr = (const float*)d_in[2];
    const float* W1   = (const float*)d_in[3];
    const float* b1   = (const float*)d_in[4];
    const float* W2   = (const float*)d_in[5];
    const float* b2   = (const float*)d_in[6];
    float* out = (float*)d_out;
    __hip_bfloat16* w1f = (__hip_bfloat16*)d_ws;   // 26*8*64*8*2 = 212992 B

    prep_w1f<<<(26 * 8 * 64 * 8 + 255) / 256, 256, 0, stream>>>(W1, w1f);
    const int nblk = (E_TOT + 127) / 128;   // 1563
    gcn_main<<<nblk, 256, 0, stream>>>(z, ei, attr, w1f, b1, W2, b2, out);
}

// Round 11
// 424.872 us; speedup vs baseline: 5.1044x; 5.1044x over previous
//
#include <hip/hip_runtime.h>
#include <hip/hip_bf16.h>

#define E_TOT 200000
#define NZ 64
#define ATTR_D 768
#define HID_D 128
#define NCLS 5
#define NAT 24          // attr K-steps of 32 floats (kt = 2..25)
#define NBLK 1563       // real tiles
#define REPS 3          // grid-replication factor (measurement round)

typedef __attribute__((ext_vector_type(8))) short short8;   // 8 bf16 (4 VGPRs)
typedef __attribute__((ext_vector_type(4))) float f32x4;    // MFMA accumulator

typedef __attribute__((address_space(3))) unsigned       lds_u32_t;
typedef const __attribute__((address_space(1))) unsigned glob_u32_t;

__device__ __forceinline__ unsigned pk2(float a, float b) {
    __hip_bfloat162 h = __float22bfloat162_rn(make_float2(a, b));
    return *reinterpret_cast<unsigned*>(&h);
}

__device__ __forceinline__ short8 pack8(const float4 x0, const float4 x1) {
    union { unsigned u[4]; short8 s; } r;
    r.u[0] = pk2(x0.x, x0.y);
    r.u[1] = pk2(x0.z, x0.w);
    r.u[2] = pk2(x1.x, x1.y);
    r.u[3] = pk2(x1.z, x1.w);
    return r.s;
}

// ---- prep: W1 [832][128] f32 -> frag-ordered bf16 w1f[kt][f][lane][8]
__global__ void prep_w1f(const float* __restrict__ W1, __hip_bfloat16* __restrict__ w1f) {
    int idx = blockIdx.x * 256 + threadIdx.x;       // 26*8*64*8 = 106496
    if (idx >= 26 * 8 * 64 * 8) return;
    int j    = idx & 7;
    int lane = (idx >> 3) & 63;
    int f    = (idx >> 9) & 7;
    int kt   = idx >> 12;
    int n = f * 16 + (lane & 15);
    int k = kt * 32 + (lane >> 4) * 8 + j;
    w1f[idx] = __float2bfloat16(W1[(size_t)k * HID_D + n]);
}

// ---- MEASUREMENT ROUND: the R3 champion kernel (174 us), work replicated via
// the GRID (tile = blockIdx.x % NBLK, rep-major dispatch) so per-block codegen
// is untouched — unlike R10's in-body rep loop which spilled (WRITE 328 MB/rep).
// All reps write identical outputs -> deterministic. Divide FETCH/WRITE by 3.
__global__ __launch_bounds__(256, 2) void gcn_main(
    const float* __restrict__ z, const int* __restrict__ ei,
    const float* __restrict__ attr, const __hip_bfloat16* __restrict__ w1f,
    const float* __restrict__ b1, const float* __restrict__ W2,
    const float* __restrict__ b2, float* __restrict__ out) {

    __shared__ float As[2][128 * 32];   // 2 x 16 KB, row = 32 f32 = 8 chunks of 16B

    const int t    = threadIdx.x;
    const int wv   = t >> 6;
    const int lane = t & 63;
    const int g    = lane >> 4;     // k-group
    const int c0   = lane & 15;
    const int e0   = (blockIdx.x % NBLK) * 128;

    // ---- staging source pointers: 4 x 16B per thread per step; LDS stays linear,
    // the chunk permutation c = p ^ (row&7) is applied to the GLOBAL source.
    const float* sbase[4];
#pragma unroll
    for (int i = 0; i < 4; ++i) {
        int L   = wv * 1024 + i * 4096 + lane * 16;   // linear LDS byte this lane covers
        int row = L >> 7;                             // 128B per row
        int p   = (L >> 4) & 7;                       // physical 16B chunk slot
        int c   = p ^ (row & 7);                      // logical chunk stored there
        int er  = e0 + row; if (er >= E_TOT) er = E_TOT - 1;
        sbase[i] = attr + (size_t)er * ATTR_D + c * 4;
    }

    auto STAGE = [&](int buf, int at) {
#pragma unroll
        for (int i = 0; i < 4; ++i) {
            __builtin_amdgcn_global_load_lds(
                (glob_u32_t*)(sbase[i] + at * 32),
                (lds_u32_t*)&As[buf][wv * 256 + i * 1024],
                16, 0, 0);
        }
    };

    const __hip_bfloat16* wf = w1f + (size_t)lane * 8;
    auto LOADB = [&](int kt, short8(&b)[8]) {
#pragma unroll
        for (int f = 0; f < 8; ++f)
            b[f] = *reinterpret_cast<const short8*>(wf + (size_t)(kt * 8 + f) * 512);
    };

    // ---- z-gather pointers (clamped; clamped rows' results never written)
    const float* zsp[2];
    const float* zdp[2];
#pragma unroll
    for (int m = 0; m < 2; ++m) {
        int e = e0 + wv * 32 + m * 16 + c0; if (e >= E_TOT) e = E_TOT - 1;
        int si = ei[e];
        int di = ei[E_TOT + e];
        zsp[m] = z + (size_t)si * NZ + g * 8;
        zdp[m] = z + (size_t)di * NZ + g * 8;
    }

    f32x4 acc[2][8];
#pragma unroll
    for (int m = 0; m < 2; ++m)
#pragma unroll
        for (int f = 0; f < 8; ++f) acc[m][f] = (f32x4){0.f, 0.f, 0.f, 0.f};

    // ---- prologue: start the attr stream ASAP, hide it behind the z-phase
    STAGE(0, 0);

    {
        short8 bz0[8], bz1[8];
        LOADB(0, bz0);
        LOADB(1, bz1);
#pragma unroll
        for (int kt = 0; kt < 2; ++kt) {
            short8 a[2];
#pragma unroll
            for (int m = 0; m < 2; ++m) {
                const float4* ps = reinterpret_cast<const float4*>(zsp[m] + kt * 32);
                const float4* pd = reinterpret_cast<const float4*>(zdp[m] + kt * 32);
                float4 s0 = ps[0], s1 = ps[1];
                float4 d0 = pd[0], d1 = pd[1];
                float4 x0 = make_float4(s0.x * d0.x, s0.y * d0.y, s0.z * d0.z, s0.w * d0.w);
                float4 x1 = make_float4(s1.x * d1.x, s1.y * d1.y, s1.z * d1.z, s1.w * d1.w);
                a[m] = pack8(x0, x1);
            }
#pragma unroll
            for (int f = 0; f < 8; ++f) {
                short8 bb = kt ? bz1[f] : bz0[f];
                acc[0][f] = __builtin_amdgcn_mfma_f32_16x16x32_bf16(a[0], bb, acc[0][f], 0, 0, 0);
                acc[1][f] = __builtin_amdgcn_mfma_f32_16x16x32_bf16(a[1], bb, acc[1][f], 0, 0, 0);
            }
        }
    }

    short8 bC[8], bN[8];
    LOADB(2, bC);
    __syncthreads();    // drains vmcnt -> buf0 staged

    // ---- main pipeline: compute at (kt=at+2) from As[cur], stage at+1 into As[cur^1]
    for (int at = 0; at < NAT; ++at) {
        const int cur = at & 1;
        if (at + 1 < NAT) STAGE(cur ^ 1, at + 1);
        const int ktn = (at + 3 <= 25) ? at + 3 : 25;
        LOADB(ktn, bN);

        short8 a[2];
#pragma unroll
        for (int m = 0; m < 2; ++m) {
            int r    = wv * 32 + m * 16 + c0;
            int base = r * 32;
            int p0   = ((g * 2)     ^ (r & 7)) * 4;
            int p1   = ((g * 2 + 1) ^ (r & 7)) * 4;
            float4 x0 = *reinterpret_cast<const float4*>(&As[cur][base + p0]);
            float4 x1 = *reinterpret_cast<const float4*>(&As[cur][base + p1]);
            a[m] = pack8(x0, x1);
        }
#pragma unroll
        for (int f = 0; f < 8; ++f) {
            acc[0][f] = __builtin_amdgcn_mfma_f32_16x16x32_bf16(a[0], bC[f], acc[0][f], 0, 0, 0);
            acc[1][f] = __builtin_amdgcn_mfma_f32_16x16x32_bf16(a[1], bC[f], acc[1][f], 0, 0, 0);
        }
        __syncthreads();    // single drain per step: next buffer staged, reads done
#pragma unroll
        for (int f = 0; f < 8; ++f) bC[f] = bN[f];
    }

    // ---- epilogue: h = relu(acc + b1); logits = h @ W2 + b2; softmax; write
    float b1v[8], w2v[8][NCLS];
#pragma unroll
    for (int f = 0; f < 8; ++f) {
        int col = f * 16 + c0;
        b1v[f] = b1[col];
#pragma unroll
        for (int cc = 0; cc < NCLS; ++cc) w2v[f][cc] = W2[col * NCLS + cc];
    }
    float b2v[NCLS];
#pragma unroll
    for (int cc = 0; cc < NCLS; ++cc) b2v[cc] = b2[cc];

#pragma unroll
    for (int m = 0; m < 2; ++m) {
#pragma unroll
        for (int i = 0; i < 4; ++i) {
            float lg[NCLS] = {0.f, 0.f, 0.f, 0.f, 0.f};
#pragma unroll
            for (int f = 0; f < 8; ++f) {
                float h = acc[m][f][i] + b1v[f];
                h = fmaxf(h, 0.f);
#pragma unroll
                for (int cc = 0; cc < NCLS; ++cc) lg[cc] = fmaf(h, w2v[f][cc], lg[cc]);
            }
#pragma unroll
            for (int mask = 1; mask < 16; mask <<= 1) {
#pragma unroll
                for (int cc = 0; cc < NCLS; ++cc) lg[cc] += __shfl_xor(lg[cc], mask);
            }
#pragma unroll
            for (int cc = 0; cc < NCLS; ++cc) lg[cc] += b2v[cc];

            float mx = fmaxf(fmaxf(fmaxf(lg[0], lg[1]), fmaxf(lg[2], lg[3])), lg[4]);
            float q[NCLS];
            float s = 0.f;
#pragma unroll
            for (int cc = 0; cc < NCLS; ++cc) { q[cc] = __expf(lg[cc] - mx); s += q[cc]; }
            float inv = 1.0f / s;
            float num = (c0 == 0) ? q[0] : (c0 == 1) ? q[1] : (c0 == 2) ? q[2]
                      : (c0 == 3) ? q[3] : q[4];
            int rowl = wv * 32 + m * 16 + g * 4 + i;
            int eo = e0 + rowl;
            if (eo < E_TOT && c0 < NCLS) out[(size_t)eo * NCLS + c0] = num * inv;
        }
    }
}

extern "C" void kernel_launch(void* const* d_in, const int* in_sizes, int n_in,
                              void* d_out, int out_size, void* d_ws, size_t ws_size,
                              hipStream_t stream) {
    const float* z    = (const float*)d_in[0];
    const int*   ei   = (const int*)d_in[1];
    const float* attr = (const float*)d_in[2];
    const float* W1   = (const float*)d_in[3];
    const float* b1   = (const float*)d_in[4];
    const float* W2   = (const float*)d_in[5];
    const float* b2   = (const float*)d_in[6];
    float* out = (float*)d_out;
    __hip_bfloat16* w1f = (__hip_bfloat16*)d_ws;   // 26*8*64*8*2 = 212992 B

    prep_w1f<<<(26 * 8 * 64 * 8 + 255) / 256, 256, 0, stream>>>(W1, w1f);
    gcn_main<<<REPS * NBLK, 256, 0, stream>>>(z, ei, attr, w1f, b1, W2, b2, out);
}